// Round 11
// baseline (329.178 us; speedup 1.0000x reference)
//
#include <hip/hip_runtime.h>
#include <stdint.h>

typedef int v4i __attribute__((ext_vector_type(4)));

#define GLD_LDS16(gp, lp)                                                              \
  __builtin_amdgcn_global_load_lds((const __attribute__((address_space(1))) void*)(gp), \
                                   (__attribute__((address_space(3))) void*)(lp), 16, 0, 0)

__device__ __forceinline__ v4i lds_read_b128(uint32_t off) {
  v4i r;
  asm volatile("ds_read_b128 %0, %1" : "=v"(r) : "v"(off));
  return r;
}

#define LGKM(N)                                              \
  do {                                                       \
    asm volatile("s_waitcnt lgkmcnt(" #N ")" ::: "memory");  \
    __builtin_amdgcn_sched_barrier(0);                       \
  } while (0)

// ---------------------------------------------------------------------------
__device__ __forceinline__ void fwht16(float v[16]) {
#pragma unroll
  for (int h = 1; h < 16; h <<= 1) {
#pragma unroll
    for (int i = 0; i < 16; ++i) {
      if (!(i & h)) {
        float a = v[i], b = v[i | h];
        v[i] = a + b;
        v[i | h] = a - b;
      }
    }
  }
}

__device__ __forceinline__ void fwht_row_load(const float* __restrict__ xr, int t,
                                              float v[16]) {
  const float4* p = reinterpret_cast<const float4*>(xr) + t * 4;
  float4 a = p[0], b = p[1], c = p[2], d = p[3];
  v[0] = a.x; v[1] = a.y; v[2] = a.z; v[3] = a.w;
  v[4] = b.x; v[5] = b.y; v[6] = b.z; v[7] = b.w;
  v[8] = c.x; v[9] = c.y; v[10] = c.z; v[11] = c.w;
  v[12] = d.x; v[13] = d.y; v[14] = d.z; v[15] = d.w;
}

__device__ __forceinline__ void fwht4096(float v[16], float* lds, int t) {
  fwht16(v);
#pragma unroll
  for (int e = 0; e < 16; ++e) {
    int idx = t * 16 + e;
    lds[idx + (idx >> 5)] = v[e];
  }
  __syncthreads();
#pragma unroll
  for (int e = 0; e < 16; ++e) {
    int idx = ((t >> 4) << 8) + (e << 4) + (t & 15);
    v[e] = lds[idx + (idx >> 5)];
  }
  fwht16(v);
#pragma unroll
  for (int e = 0; e < 16; ++e) {
    int idx = ((t >> 4) << 8) + (e << 4) + (t & 15);
    lds[idx + (idx >> 5)] = v[e];
  }
  __syncthreads();
#pragma unroll
  for (int e = 0; e < 16; ++e) {
    int idx = (e << 8) + t;
    v[e] = lds[idx + (idx >> 5)];
  }
  fwht16(v);
#pragma unroll
  for (int e = 0; e < 16; ++e) v[e] *= 0.015625f;  // 1/sqrt(4096)
}

__global__ __launch_bounds__(256) void fwht_quant_kernel(const float* __restrict__ X,
                                                         int8_t* __restrict__ Q,
                                                         float* __restrict__ S) {
  const int row = blockIdx.x;
  const int t = threadIdx.x;
  __shared__ float lds[4224];
  __shared__ float wred[4];

  float v[16];
  fwht_row_load(X + (size_t)row * 4096, t, v);
  fwht4096(v, lds, t);

  float m = 0.f;
#pragma unroll
  for (int e = 0; e < 16; ++e) m = fmaxf(m, fabsf(v[e]));
#pragma unroll
  for (int off = 32; off > 0; off >>= 1) m = fmaxf(m, __shfl_xor(m, off));
  if ((t & 63) == 0) wred[t >> 6] = m;
  __syncthreads();
  m = fmaxf(fmaxf(wred[0], wred[1]), fmaxf(wred[2], wred[3]));
  const float s = fmaxf(m * (1.0f / 127.0f), 1e-8f);
  if (t == 0) S[row] = s;
  int8_t* qr = Q + (size_t)row * 4096;
#pragma unroll
  for (int e = 0; e < 16; ++e) {
    float q = rintf(v[e] / s);
    q = fminf(fmaxf(q, -127.f), 127.f);
    qr[(e << 8) + t] = (int8_t)(int)q;
  }
}

// ---------------------------------------------------------------------------
// tq[kc] partial = qx @ qa^T over k-chunk kc (512 bytes, 8 MFMA steps). Exact int32.
__global__ __launch_bounds__(256) void lora_mfma_kernel(const int8_t* __restrict__ Qx,
                                                        const int8_t* __restrict__ Qa,
                                                        int* __restrict__ tqp) {
  const int lane = threadIdx.x & 63;
  const int wv = threadIdx.x >> 6;            // 0..3
  const int m0 = (blockIdx.x * 4 + wv) * 16;  // row-tile base
  const int kc = blockIdx.y;                  // 0..7
  const int8_t* ax =
      Qx + (size_t)(m0 + (lane & 15)) * 4096 + kc * 512 + ((lane >> 4) << 4);
  const int8_t* bx = Qa + (size_t)(lane & 15) * 4096 + kc * 512 + ((lane >> 4) << 4);
  v4i acc = {0, 0, 0, 0};
#pragma unroll
  for (int s = 0; s < 8; ++s) {
    v4i a = *reinterpret_cast<const v4i*>(ax + s * 64);
    v4i b = *reinterpret_cast<const v4i*>(bx + s * 64);
    acc = __builtin_amdgcn_mfma_i32_16x16x64_i8(a, b, acc, 0, 0, 0);
  }
  int* tp = tqp + ((size_t)kc * 8192 + m0) * 16;
#pragma unroll
  for (int rr = 0; rr < 4; ++rr)
    tp[((lane >> 4) * 4 + rr) * 16 + (lane & 15)] = acc[rr];  // C/D: col=l&15
}

__global__ __launch_bounds__(256) void lora_t_reduce_kernel(const int* __restrict__ tqp,
                                                            const float* __restrict__ Sx,
                                                            const float* __restrict__ Sa,
                                                            float* __restrict__ tmat) {
  int i = blockIdx.x * 256 + threadIdx.x;  // 131072 = 8192*16
  int row = i >> 4, r = i & 15;
  int s = 0;
#pragma unroll
  for (int kc = 0; kc < 8; ++kc) s += tqp[(size_t)kc * 131072 + i];
  tmat[i] = (float)s * Sx[row] * Sa[r];
}

// ---------------------------------------------------------------------------
// 256x128 i8 GEMM. R7 geometry (3-ring 72KB, 2 blocks/CU, never-drain vmcnt(3))
// with the conflict-clean mfma_i32_16x16x64_i8 layout (R5/R8/R10: ~200K
// conflicts vs 17M for 32x32). 8 waves = 4M x 2N, per-wave 64x64
// (acc 4x4 v4i = 64 AGPR). REGISTER BUDGET 128/thread enforced: no bf-preload
// (fine lgkm ladder instead), epilogue split in 2 ni-halves (blv[2][16]) --
// R10's identical structure spilled ~370MB scratch from exactly these two.
// Per step (BK=64B): stage(t+2) [3 gld_lds]; read bf0-3,af0-3;
// lgkm(3) mi0; lgkm(2) mi1; lgkm(1) mi2; lgkm(0) mi3; vmcnt(3); barrier.
__global__ __launch_bounds__(512, 4) void gemm_i8_kernel(
    const int8_t* __restrict__ Aq, const int8_t* __restrict__ Bq,
    const float* __restrict__ Sx, const float* __restrict__ Sw,
    const float* __restrict__ Tm, const float* __restrict__ LB,
    float* __restrict__ out) {
  __shared__ __align__(16) char smem[73728];  // 3 x (A 16K + B 8K)

  const int tid = threadIdx.x;
  const int lane = tid & 63;
  const int w = tid >> 6;   // 0..7
  const int wm = w >> 1;    // 0..3 (M quadrant)
  const int wn = w & 1;     // 0..1 (N half)

  int bid = (int)blockIdx.x;
  bid = (bid & 7) * 128 + (bid >> 3);  // bijective XCD swizzle (1024 % 8 == 0)
  const int bm = bid >> 5;             // 0..31
  const int bn = bid & 31;             // 0..31

  const int8_t* Ag = Aq + (size_t)bm * 256 * 4096;
  const int8_t* Bg = Bq + (size_t)bn * 128 * 4096;

  const uint32_t sbase = (uint32_t)(uintptr_t)(void*)smem;

  // ---- staging: 3 loads/wave/step; pre-swizzled source chunk (R5-proven) ----
  const uint32_t srcOff = (uint32_t)(((lane & 3) ^ ((lane >> 3) & 3)) << 4);
  const uint32_t gA0 = (uint32_t)((w * 32 + (lane >> 2)) * 4096) + srcOff;
  const uint32_t gA1 = gA0 + 16 * 4096;
  const uint32_t gB0 = (uint32_t)((w * 16 + (lane >> 2)) * 4096) + srcOff;

#define STAGE_STEP(s, bufbase)                                           \
  do {                                                                   \
    const uint32_t kb = (uint32_t)(s) << 6;                              \
    GLD_LDS16(Ag + kb + gA0, smem + (bufbase) + w * 2048);               \
    GLD_LDS16(Ag + kb + gA1, smem + (bufbase) + w * 2048 + 1024);        \
    GLD_LDS16(Bg + kb + gB0, smem + (bufbase) + 16384 + w * 1024);       \
  } while (0)

  // ---- fragment LDS offsets (16x16x64: rows lane&15, chunk lane>>4) ----
  int aoff[4], boff[4];
  const int cc = lane >> 4;
#pragma unroll
  for (int mi = 0; mi < 4; ++mi) {
    int r = wm * 64 + mi * 16 + (lane & 15);
    aoff[mi] = r * 64 + ((cc ^ ((r >> 1) & 3)) << 4);
  }
#pragma unroll
  for (int ni = 0; ni < 4; ++ni) {
    int r = wn * 64 + ni * 16 + (lane & 15);
    boff[ni] = 16384 + r * 64 + ((cc ^ ((r >> 1) & 3)) << 4);
  }

  v4i acc[4][4];
#pragma unroll
  for (int i = 0; i < 4; ++i)
#pragma unroll
    for (int n = 0; n < 4; ++n) {
      v4i z = {0, 0, 0, 0};
      acc[i][n] = z;
    }

#define MFMA_ROW(MI)                                                          \
  do {                                                                        \
    _Pragma("unroll") for (int n = 0; n < 4; ++n)                             \
        acc[(MI)][n] = __builtin_amdgcn_mfma_i32_16x16x64_i8(                 \
            af[(MI)], bf[n], acc[(MI)][n], 0, 0, 0);                          \
  } while (0)

  // ---- prologue: stage 0,1 ----
  STAGE_STEP(0, 0);
  STAGE_STEP(1, 24576);
  asm volatile("s_waitcnt vmcnt(3)" ::: "memory");  // stage 0 landed
  __builtin_amdgcn_s_barrier();
  __builtin_amdgcn_sched_barrier(0);

  uint32_t bc = 0, bn1 = 24576, bn2 = 49152;

#pragma unroll 1
  for (int t = 0; t < 64; ++t) {
    if (t <= 61) STAGE_STEP(t + 2, bn2);

    const uint32_t R = sbase + bc;
    v4i af[4], bf[4];
    bf[0] = lds_read_b128(R + boff[0]);
    bf[1] = lds_read_b128(R + boff[1]);
    bf[2] = lds_read_b128(R + boff[2]);
    bf[3] = lds_read_b128(R + boff[3]);
    af[0] = lds_read_b128(R + aoff[0]);
    af[1] = lds_read_b128(R + aoff[1]);
    af[2] = lds_read_b128(R + aoff[2]);
    af[3] = lds_read_b128(R + aoff[3]);

    __builtin_amdgcn_s_setprio(1);
    LGKM(3);  // bf0-3 + af0 ready; af1-3 still flying under MFMAs
    MFMA_ROW(0);
    LGKM(2);
    MFMA_ROW(1);
    LGKM(1);
    MFMA_ROW(2);
    LGKM(0);
    MFMA_ROW(3);
    __builtin_amdgcn_s_setprio(0);

    // never-drain: stage(t+1) landed; t+2 stays in flight
    if (t <= 61)
      asm volatile("s_waitcnt vmcnt(3)" ::: "memory");
    else if (t == 62)
      asm volatile("s_waitcnt vmcnt(0)" ::: "memory");
    __builtin_amdgcn_s_barrier();  // buf(t+1) published everywhere
    __builtin_amdgcn_sched_barrier(0);

    uint32_t tmp = bc;  // ring rotate
    bc = bn1;
    bn1 = bn2;
    bn2 = tmp;
  }

  // ---- epilogue: scales + fused LoRA (register-light: 2 ni-halves) ----
  __syncthreads();
  float* tl = (float*)smem;              // [256][17]
  float* bl = (float*)(smem + 17408);    // [128][17]
  for (int i = tid; i < 1024; i += 512) {
    int r = i >> 2, q4 = (i & 3) * 4;
    float4 tv = *reinterpret_cast<const float4*>(Tm + (size_t)(bm * 256 + r) * 16 + q4);
    tl[r * 17 + q4 + 0] = tv.x;
    tl[r * 17 + q4 + 1] = tv.y;
    tl[r * 17 + q4 + 2] = tv.z;
    tl[r * 17 + q4 + 3] = tv.w;
  }
  if (tid < 512) {
    int r = tid >> 2, q4 = (tid & 3) * 4;
    float4 bv = *reinterpret_cast<const float4*>(LB + (size_t)(bn * 128 + r) * 16 + q4);
    bl[r * 17 + q4 + 0] = bv.x;
    bl[r * 17 + q4 + 1] = bv.y;
    bl[r * 17 + q4 + 2] = bv.z;
    bl[r * 17 + q4 + 3] = bv.w;
  }
  __syncthreads();

#pragma unroll
  for (int h = 0; h < 2; ++h) {  // ni pair {2h, 2h+1}: blv only 32 regs live
    float blv[2][16], swv[2];
#pragma unroll
    for (int p = 0; p < 2; ++p) {
      int cl = wn * 64 + (h * 2 + p) * 16 + (lane & 15);
      swv[p] = Sw[bn * 128 + cl];
#pragma unroll
      for (int q = 0; q < 16; ++q) blv[p][q] = bl[cl * 17 + q];
    }
#pragma unroll
    for (int mi = 0; mi < 4; ++mi) {
#pragma unroll
      for (int rr = 0; rr < 4; ++rr) {
        int rl = wm * 64 + mi * 16 + (lane >> 4) * 4 + rr;  // C/D row=(l>>4)*4+reg
        float sxv = Sx[bm * 256 + rl];
        float tv[16];
#pragma unroll
        for (int q = 0; q < 16; ++q) tv[q] = tl[rl * 17 + q];
        float* orow = out + (size_t)(bm * 256 + rl) * 4096 + bn * 128;
#pragma unroll
        for (int p = 0; p < 2; ++p) {
          float dot = 0.f;
#pragma unroll
          for (int q = 0; q < 16; ++q) dot = fmaf(tv[q], blv[p][q], dot);
          int cl = wn * 64 + (h * 2 + p) * 16 + (lane & 15);  // C/D col=l&15
          orow[cl] = sxv * swv[p] * (float)acc[mi][h * 2 + p][rr] + 2.0f * dot;
        }
      }
    }
  }
}

// ---------------------------------------------------------------------------
extern "C" void kernel_launch(void* const* d_in, const int* in_sizes, int n_in,
                              void* d_out, int out_size, void* d_ws, size_t ws_size,
                              hipStream_t stream) {
  const float* x = (const float*)d_in[0];     // 8192 x 4096
  const float* wgt = (const float*)d_in[1];   // 4096 x 4096
  const float* lA = (const float*)d_in[2];    // 16 x 4096
  const float* lB = (const float*)d_in[3];    // 4096 x 16
  float* out = (float*)d_out;                 // 8192 x 4096

  char* ws = (char*)d_ws;
  int8_t* qx = (int8_t*)ws;                    // 32 MB
  int8_t* qw = (int8_t*)(ws + 33554432);       // 16 MB
  float* sx = (float*)(ws + 50331648);         // 32 KB
  float* sw = (float*)(ws + 50364416);         // 16 KB
  float* tmat = (float*)(ws + 50380800);       // 512 KB
  int* tqp = (int*)(ws + 50905088);            // 4 MB int32 partials
  int8_t* qa = (int8_t*)(ws + 55099392);       // 64 KB
  float* sa = (float*)(ws + 55164928);         // 64 B

  fwht_quant_kernel<<<8192, 256, 0, stream>>>(x, qx, sx);
  fwht_quant_kernel<<<4096, 256, 0, stream>>>(wgt, qw, sw);
  fwht_quant_kernel<<<16, 256, 0, stream>>>(lA, qa, sa);
  lora_mfma_kernel<<<dim3(128, 8), 256, 0, stream>>>(qx, qa, tqp);
  lora_t_reduce_kernel<<<512, 256, 0, stream>>>(tqp, sx, sa, tmat);
  gemm_i8_kernel<<<1024, 512, 0, stream>>>(qx, qw, sx, sw, tmat, lB, out);
}

// Round 12
// 272.556 us; speedup vs baseline: 1.2077x; 1.2077x over previous
//
#include <hip/hip_runtime.h>
#include <stdint.h>

typedef int v4i __attribute__((ext_vector_type(4)));

#define GLD_LDS16(gp, lp)                                                              \
  __builtin_amdgcn_global_load_lds((const __attribute__((address_space(1))) void*)(gp), \
                                   (__attribute__((address_space(3))) void*)(lp), 16, 0, 0)

__device__ __forceinline__ v4i lds_read_b128(uint32_t off) {
  v4i r;
  asm volatile("ds_read_b128 %0, %1" : "=v"(r) : "v"(off));
  return r;
}

#define LGKM(N)                                              \
  do {                                                       \
    asm volatile("s_waitcnt lgkmcnt(" #N ")" ::: "memory");  \
    __builtin_amdgcn_sched_barrier(0);                       \
  } while (0)

// ---------------------------------------------------------------------------
__device__ __forceinline__ void fwht16(float v[16]) {
#pragma unroll
  for (int h = 1; h < 16; h <<= 1) {
#pragma unroll
    for (int i = 0; i < 16; ++i) {
      if (!(i & h)) {
        float a = v[i], b = v[i | h];
        v[i] = a + b;
        v[i | h] = a - b;
      }
    }
  }
}

__device__ __forceinline__ void fwht_row_load(const float* __restrict__ xr, int t,
                                              float v[16]) {
  const float4* p = reinterpret_cast<const float4*>(xr) + t * 4;
  float4 a = p[0], b = p[1], c = p[2], d = p[3];
  v[0] = a.x; v[1] = a.y; v[2] = a.z; v[3] = a.w;
  v[4] = b.x; v[5] = b.y; v[6] = b.z; v[7] = b.w;
  v[8] = c.x; v[9] = c.y; v[10] = c.z; v[11] = c.w;
  v[12] = d.x; v[13] = d.y; v[14] = d.z; v[15] = d.w;
}

__device__ __forceinline__ void fwht4096(float v[16], float* lds, int t) {
  fwht16(v);
#pragma unroll
  for (int e = 0; e < 16; ++e) {
    int idx = t * 16 + e;
    lds[idx + (idx >> 5)] = v[e];
  }
  __syncthreads();
#pragma unroll
  for (int e = 0; e < 16; ++e) {
    int idx = ((t >> 4) << 8) + (e << 4) + (t & 15);
    v[e] = lds[idx + (idx >> 5)];
  }
  fwht16(v);
#pragma unroll
  for (int e = 0; e < 16; ++e) {
    int idx = ((t >> 4) << 8) + (e << 4) + (t & 15);
    lds[idx + (idx >> 5)] = v[e];
  }
  __syncthreads();
#pragma unroll
  for (int e = 0; e < 16; ++e) {
    int idx = (e << 8) + t;
    v[e] = lds[idx + (idx >> 5)];
  }
  fwht16(v);
#pragma unroll
  for (int e = 0; e < 16; ++e) v[e] *= 0.015625f;  // 1/sqrt(4096)
}

__global__ __launch_bounds__(256) void fwht_quant_kernel(const float* __restrict__ X,
                                                         int8_t* __restrict__ Q,
                                                         float* __restrict__ S) {
  const int row = blockIdx.x;
  const int t = threadIdx.x;
  __shared__ float lds[4224];
  __shared__ float wred[4];

  float v[16];
  fwht_row_load(X + (size_t)row * 4096, t, v);
  fwht4096(v, lds, t);

  float m = 0.f;
#pragma unroll
  for (int e = 0; e < 16; ++e) m = fmaxf(m, fabsf(v[e]));
#pragma unroll
  for (int off = 32; off > 0; off >>= 1) m = fmaxf(m, __shfl_xor(m, off));
  if ((t & 63) == 0) wred[t >> 6] = m;
  __syncthreads();
  m = fmaxf(fmaxf(wred[0], wred[1]), fmaxf(wred[2], wred[3]));
  const float s = fmaxf(m * (1.0f / 127.0f), 1e-8f);
  if (t == 0) S[row] = s;
  int8_t* qr = Q + (size_t)row * 4096;
#pragma unroll
  for (int e = 0; e < 16; ++e) {
    float q = rintf(v[e] / s);
    q = fminf(fmaxf(q, -127.f), 127.f);
    qr[(e << 8) + t] = (int8_t)(int)q;
  }
}

// ---------------------------------------------------------------------------
// tq[kc] partial = qx @ qa^T over k-chunk kc (512 bytes, 8 MFMA steps). Exact int32.
__global__ __launch_bounds__(256) void lora_mfma_kernel(const int8_t* __restrict__ Qx,
                                                        const int8_t* __restrict__ Qa,
                                                        int* __restrict__ tqp) {
  const int lane = threadIdx.x & 63;
  const int wv = threadIdx.x >> 6;            // 0..3
  const int m0 = (blockIdx.x * 4 + wv) * 16;  // row-tile base
  const int kc = blockIdx.y;                  // 0..7
  const int8_t* ax =
      Qx + (size_t)(m0 + (lane & 15)) * 4096 + kc * 512 + ((lane >> 4) << 4);
  const int8_t* bx = Qa + (size_t)(lane & 15) * 4096 + kc * 512 + ((lane >> 4) << 4);
  v4i acc = {0, 0, 0, 0};
#pragma unroll
  for (int s = 0; s < 8; ++s) {
    v4i a = *reinterpret_cast<const v4i*>(ax + s * 64);
    v4i b = *reinterpret_cast<const v4i*>(bx + s * 64);
    acc = __builtin_amdgcn_mfma_i32_16x16x64_i8(a, b, acc, 0, 0, 0);
  }
  int* tp = tqp + ((size_t)kc * 8192 + m0) * 16;
#pragma unroll
  for (int rr = 0; rr < 4; ++rr)
    tp[((lane >> 4) * 4 + rr) * 16 + (lane & 15)] = acc[rr];  // C/D: col=l&15
}

__global__ __launch_bounds__(256) void lora_t_reduce_kernel(const int* __restrict__ tqp,
                                                            const float* __restrict__ Sx,
                                                            const float* __restrict__ Sa,
                                                            float* __restrict__ tmat) {
  int i = blockIdx.x * 256 + threadIdx.x;  // 131072 = 8192*16
  int row = i >> 4, r = i & 15;
  int s = 0;
#pragma unroll
  for (int kc = 0; kc < 8; ++kc) s += tqp[(size_t)kc * 131072 + i];
  tmat[i] = (float)s * Sx[row] * Sa[r];
}

// ---------------------------------------------------------------------------
// 256x128 i8 GEMM. R7 geometry (3-ring 72KB, never-drain vmcnt(3)) with the
// conflict-clean mfma_i32_16x16x64_i8 layout. 8 waves = 4M x 2N, per-wave
// 64x64 (acc 4x4 v4i = 64 AGPR).
// LAUNCH BOUNDS (512,2): R7 proved the natural allocation is ~128 total regs
// -> 2 blocks/CU without forcing; declaring (512,4) in R10/R11 capped the
// allocator at 128 and spilled ~370MB scratch. Do not constrain below the
// natural footprint.
__global__ __launch_bounds__(512, 2) void gemm_i8_kernel(
    const int8_t* __restrict__ Aq, const int8_t* __restrict__ Bq,
    const float* __restrict__ Sx, const float* __restrict__ Sw,
    const float* __restrict__ Tm, const float* __restrict__ LB,
    float* __restrict__ out) {
  __shared__ __align__(16) char smem[73728];  // 3 x (A 16K + B 8K)

  const int tid = threadIdx.x;
  const int lane = tid & 63;
  const int w = tid >> 6;   // 0..7
  const int wm = w >> 1;    // 0..3 (M quadrant)
  const int wn = w & 1;     // 0..1 (N half)

  int bid = (int)blockIdx.x;
  bid = (bid & 7) * 128 + (bid >> 3);  // bijective XCD swizzle (1024 % 8 == 0)
  const int bm = bid >> 5;             // 0..31
  const int bn = bid & 31;             // 0..31

  const int8_t* Ag = Aq + (size_t)bm * 256 * 4096;
  const int8_t* Bg = Bq + (size_t)bn * 128 * 4096;

  const uint32_t sbase = (uint32_t)(uintptr_t)(void*)smem;

  // ---- staging: 3 loads/wave/step; pre-swizzled source chunk (R5-proven) ----
  const uint32_t srcOff = (uint32_t)(((lane & 3) ^ ((lane >> 3) & 3)) << 4);
  const uint32_t gA0 = (uint32_t)((w * 32 + (lane >> 2)) * 4096) + srcOff;
  const uint32_t gA1 = gA0 + 16 * 4096;
  const uint32_t gB0 = (uint32_t)((w * 16 + (lane >> 2)) * 4096) + srcOff;

#define STAGE_STEP(s, bufbase)                                           \
  do {                                                                   \
    const uint32_t kb = (uint32_t)(s) << 6;                              \
    GLD_LDS16(Ag + kb + gA0, smem + (bufbase) + w * 2048);               \
    GLD_LDS16(Ag + kb + gA1, smem + (bufbase) + w * 2048 + 1024);        \
    GLD_LDS16(Bg + kb + gB0, smem + (bufbase) + 16384 + w * 1024);       \
  } while (0)

  // ---- fragment LDS offsets (16x16x64: rows lane&15, chunk lane>>4) ----
  int aoff[4], boff[4];
  const int cc = lane >> 4;
#pragma unroll
  for (int mi = 0; mi < 4; ++mi) {
    int r = wm * 64 + mi * 16 + (lane & 15);
    aoff[mi] = r * 64 + ((cc ^ ((r >> 1) & 3)) << 4);
  }
#pragma unroll
  for (int ni = 0; ni < 4; ++ni) {
    int r = wn * 64 + ni * 16 + (lane & 15);
    boff[ni] = 16384 + r * 64 + ((cc ^ ((r >> 1) & 3)) << 4);
  }

  v4i acc[4][4];
#pragma unroll
  for (int i = 0; i < 4; ++i)
#pragma unroll
    for (int n = 0; n < 4; ++n) {
      v4i z = {0, 0, 0, 0};
      acc[i][n] = z;
    }

#define MFMA_ROW(MI)                                                          \
  do {                                                                        \
    _Pragma("unroll") for (int n = 0; n < 4; ++n)                             \
        acc[(MI)][n] = __builtin_amdgcn_mfma_i32_16x16x64_i8(                 \
            af[(MI)], bf[n], acc[(MI)][n], 0, 0, 0);                          \
  } while (0)

  // ---- prologue: stage 0,1 ----
  STAGE_STEP(0, 0);
  STAGE_STEP(1, 24576);
  asm volatile("s_waitcnt vmcnt(3)" ::: "memory");  // stage 0 landed
  __builtin_amdgcn_s_barrier();
  __builtin_amdgcn_sched_barrier(0);

  uint32_t bc = 0, bn1 = 24576, bn2 = 49152;

#pragma unroll 1
  for (int t = 0; t < 64; ++t) {
    if (t <= 61) STAGE_STEP(t + 2, bn2);

    const uint32_t R = sbase + bc;
    v4i af[4], bf[4];
    bf[0] = lds_read_b128(R + boff[0]);
    bf[1] = lds_read_b128(R + boff[1]);
    bf[2] = lds_read_b128(R + boff[2]);
    bf[3] = lds_read_b128(R + boff[3]);
    af[0] = lds_read_b128(R + aoff[0]);
    af[1] = lds_read_b128(R + aoff[1]);
    af[2] = lds_read_b128(R + aoff[2]);
    af[3] = lds_read_b128(R + aoff[3]);

    __builtin_amdgcn_s_setprio(1);
    LGKM(3);  // bf0-3 + af0 ready; af1-3 still flying under MFMAs
    MFMA_ROW(0);
    LGKM(2);
    MFMA_ROW(1);
    LGKM(1);
    MFMA_ROW(2);
    LGKM(0);
    MFMA_ROW(3);
    __builtin_amdgcn_s_setprio(0);

    // never-drain: stage(t+1) landed; t+2 stays in flight
    if (t <= 61)
      asm volatile("s_waitcnt vmcnt(3)" ::: "memory");
    else if (t == 62)
      asm volatile("s_waitcnt vmcnt(0)" ::: "memory");
    __builtin_amdgcn_s_barrier();  // buf(t+1) published everywhere
    __builtin_amdgcn_sched_barrier(0);

    uint32_t tmp = bc;  // ring rotate
    bc = bn1;
    bn1 = bn2;
    bn2 = tmp;
  }

  // ---- epilogue: scales + fused LoRA ----
  __syncthreads();
  float* tl = (float*)smem;              // [256][17]
  float* bl = (float*)(smem + 17408);    // [128][17]
  for (int i = tid; i < 1024; i += 512) {
    int r = i >> 2, q4 = (i & 3) * 4;
    float4 tv = *reinterpret_cast<const float4*>(Tm + (size_t)(bm * 256 + r) * 16 + q4);
    tl[r * 17 + q4 + 0] = tv.x;
    tl[r * 17 + q4 + 1] = tv.y;
    tl[r * 17 + q4 + 2] = tv.z;
    tl[r * 17 + q4 + 3] = tv.w;
  }
  if (tid < 512) {
    int r = tid >> 2, q4 = (tid & 3) * 4;
    float4 bv = *reinterpret_cast<const float4*>(LB + (size_t)(bn * 128 + r) * 16 + q4);
    bl[r * 17 + q4 + 0] = bv.x;
    bl[r * 17 + q4 + 1] = bv.y;
    bl[r * 17 + q4 + 2] = bv.z;
    bl[r * 17 + q4 + 3] = bv.w;
  }
  __syncthreads();

#pragma unroll
  for (int h = 0; h < 2; ++h) {  // ni pair {2h, 2h+1}
    float blv[2][16], swv[2];
#pragma unroll
    for (int p = 0; p < 2; ++p) {
      int cl = wn * 64 + (h * 2 + p) * 16 + (lane & 15);
      swv[p] = Sw[bn * 128 + cl];
#pragma unroll
      for (int q = 0; q < 16; ++q) blv[p][q] = bl[cl * 17 + q];
    }
#pragma unroll
    for (int mi = 0; mi < 4; ++mi) {
#pragma unroll
      for (int rr = 0; rr < 4; ++rr) {
        int rl = wm * 64 + mi * 16 + (lane >> 4) * 4 + rr;  // C/D row=(l>>4)*4+reg
        float sxv = Sx[bm * 256 + rl];
        float tv[16];
#pragma unroll
        for (int q = 0; q < 16; ++q) tv[q] = tl[rl * 17 + q];
        float* orow = out + (size_t)(bm * 256 + rl) * 4096 + bn * 128;
#pragma unroll
        for (int p = 0; p < 2; ++p) {
          float dot = 0.f;
#pragma unroll
          for (int q = 0; q < 16; ++q) dot = fmaf(tv[q], blv[p][q], dot);
          int cl = wn * 64 + (h * 2 + p) * 16 + (lane & 15);  // C/D col=l&15
          orow[cl] = sxv * swv[p] * (float)acc[mi][h * 2 + p][rr] + 2.0f * dot;
        }
      }
    }
  }
}

// ---------------------------------------------------------------------------
extern "C" void kernel_launch(void* const* d_in, const int* in_sizes, int n_in,
                              void* d_out, int out_size, void* d_ws, size_t ws_size,
                              hipStream_t stream) {
  const float* x = (const float*)d_in[0];     // 8192 x 4096
  const float* wgt = (const float*)d_in[1];   // 4096 x 4096
  const float* lA = (const float*)d_in[2];    // 16 x 4096
  const float* lB = (const float*)d_in[3];    // 4096 x 16
  float* out = (float*)d_out;                 // 8192 x 4096

  char* ws = (char*)d_ws;
  int8_t* qx = (int8_t*)ws;                    // 32 MB
  int8_t* qw = (int8_t*)(ws + 33554432);       // 16 MB
  float* sx = (float*)(ws + 50331648);         // 32 KB
  float* sw = (float*)(ws + 50364416);         // 16 KB
  float* tmat = (float*)(ws + 50380800);       // 512 KB
  int* tqp = (int*)(ws + 50905088);            // 4 MB int32 partials
  int8_t* qa = (int8_t*)(ws + 55099392);       // 64 KB
  float* sa = (float*)(ws + 55164928);         // 64 B

  fwht_quant_kernel<<<8192, 256, 0, stream>>>(x, qx, sx);
  fwht_quant_kernel<<<4096, 256, 0, stream>>>(wgt, qw, sw);
  fwht_quant_kernel<<<16, 256, 0, stream>>>(lA, qa, sa);
  lora_mfma_kernel<<<dim3(128, 8), 256, 0, stream>>>(qx, qa, tqp);
  lora_t_reduce_kernel<<<512, 256, 0, stream>>>(tqp, sx, sa, tmat);
  gemm_i8_kernel<<<1024, 512, 0, stream>>>(qx, qw, sx, sw, tmat, lB, out);
}